// Round 1
// baseline (503.320 us; speedup 1.0000x reference)
//
#include <hip/hip_runtime.h>
#include <hip/hip_bf16.h>
#include <stdint.h>

// ---- problem constants ----
constexpr int D  = 1024;
constexpr int H  = 16;
constexpr int DH = 64;
constexpr int B  = 4;
constexpr int S  = 2048;
constexpr int BS = B * S;          // 8192
constexpr int NQKV = 3 * D;        // 3072

typedef __attribute__((ext_vector_type(8))) short bf16x8;
typedef __attribute__((ext_vector_type(4))) float f32x4;
typedef __attribute__((ext_vector_type(4))) unsigned short us4;
typedef unsigned short ushort_t;

using gu32 = __attribute__((address_space(1))) unsigned int;
using lu32 = __attribute__((address_space(3))) unsigned int;

__device__ __forceinline__ void gload_lds16(const void* g, void* l) {
  __builtin_amdgcn_global_load_lds((gu32*)g, (lu32*)l, 16, 0, 0);
}

__device__ __forceinline__ ushort_t f2bf(float f) {
  uint32_t u = __builtin_bit_cast(uint32_t, f);
  u += 0x7FFFu + ((u >> 16) & 1u);
  return (ushort_t)(u >> 16);
}
__device__ __forceinline__ float bf2f(ushort_t h) {
  return __builtin_bit_cast(float, (uint32_t)h << 16);
}

// ---------------- conversion kernels ----------------
__global__ __launch_bounds__(256) void k_conv_x(const float* __restrict__ x,
                                                ushort_t* __restrict__ xb) {
  int i = (blockIdx.x * 256 + threadIdx.x) * 4;
  float4 v = *(const float4*)(x + i);
  us4 o;
  o[0] = f2bf(v.x); o[1] = f2bf(v.y); o[2] = f2bf(v.z); o[3] = f2bf(v.w);
  *(us4*)(xb + i) = o;
}

// Wcat_t [3072][1024] bf16: row c -> (Wq|Wk|Wv)[h, d, e] with h=cl>>6, e=cl&63
__global__ __launch_bounds__(256) void k_conv_w(const float* __restrict__ Wq,
                                                const float* __restrict__ Wk,
                                                const float* __restrict__ Wv,
                                                ushort_t* __restrict__ wt) {
  int idx = blockIdx.x * 256 + threadIdx.x;   // 3072*1024
  int c = idx >> 10, d = idx & 1023;
  int cl = c & 1023;
  int hh = cl >> 6, e = cl & 63;
  const float* src = (c < 1024) ? Wq : ((c < 2048) ? Wk : Wv);
  wt[idx] = f2bf(src[(hh * D + d) * DH + e]);
}

// Wo_t [1024][1024] bf16: wot[c][d] = Wo[d][c]
__global__ __launch_bounds__(256) void k_conv_wo(const float* __restrict__ Wo,
                                                 ushort_t* __restrict__ wot) {
  int idx = blockIdx.x * 256 + threadIdx.x;   // 1024*1024
  int c = idx >> 10, d = idx & 1023;
  wot[idx] = f2bf(Wo[d * D + c]);
}

// ---------------- GEMM core: C[128,128] tile = A[M,K] @ Bt[N,K]^T (bf16) ----------------
// 256 threads = 4 waves in 2x2; wave computes 64x64 = 4x4 frags of 16x16x32 MFMA.
__device__ __forceinline__ void gemm_core_128(const ushort_t* __restrict__ A,
                                              const ushort_t* __restrict__ Bt,
                                              int K, int m0, int n0,
                                              f32x4 acc[4][4], char* lds) {
  const int t    = threadIdx.x;
  const int lane = t & 63;
  const int w    = t >> 6;
  const int wm   = w >> 1, wn = w & 1;
  const int lrow = lane & 15, lgk = (lane >> 4) * 16;   // byte offset in 64B K-row

#pragma unroll
  for (int i = 0; i < 4; i++)
#pragma unroll
    for (int j = 0; j < 4; j++) acc[i][j] = f32x4{0.f, 0.f, 0.f, 0.f};

  char* ldsA = lds;            // [128][64B]
  char* ldsB = lds + 8192;
  const long strideK = (long)K * 2;
  const char* gA = (const char*)A + (long)(m0 + (t >> 2)) * strideK + (t & 3) * 16;
  const char* gB = (const char*)Bt + (long)(n0 + (t >> 2)) * strideK + (t & 3) * 16;

  for (int kt = 0; kt < K; kt += 32) {
    const char* sA = gA + kt * 2;
    const char* sB = gB + kt * 2;
    gload_lds16(sA,                ldsA + w * 1024);
    gload_lds16(sA + 64 * strideK, ldsA + 4096 + w * 1024);
    gload_lds16(sB,                ldsB + w * 1024);
    gload_lds16(sB + 64 * strideK, ldsB + 4096 + w * 1024);
    __syncthreads();

    bf16x8 af[4], bfr[4];
#pragma unroll
    for (int mi = 0; mi < 4; mi++)
      af[mi] = *(const bf16x8*)(ldsA + (wm * 64 + mi * 16 + lrow) * 64 + lgk);
#pragma unroll
    for (int ni = 0; ni < 4; ni++)
      bfr[ni] = *(const bf16x8*)(ldsB + (wn * 64 + ni * 16 + lrow) * 64 + lgk);
#pragma unroll
    for (int mi = 0; mi < 4; mi++)
#pragma unroll
      for (int ni = 0; ni < 4; ni++)
        acc[mi][ni] = __builtin_amdgcn_mfma_f32_16x16x32_bf16(af[mi], bfr[ni], acc[mi][ni], 0, 0, 0);
    __syncthreads();
  }
}

// QKV GEMM: C[8192,3072]; epilogue adds bias, scatters Q,K -> [B,H,S,64], V -> [B,H,64,S]
__global__ __launch_bounds__(256) void k_qkv_gemm(const ushort_t* __restrict__ xb,
                                                  const ushort_t* __restrict__ wt,
                                                  const float* __restrict__ bq,
                                                  const float* __restrict__ bk,
                                                  const float* __restrict__ bv,
                                                  ushort_t* __restrict__ q_ws,
                                                  ushort_t* __restrict__ k_ws,
                                                  ushort_t* __restrict__ vT_ws) {
  __shared__ char lds[16384];
  const int m0 = blockIdx.y * 128, n0 = blockIdx.x * 128;
  f32x4 acc[4][4];
  gemm_core_128(xb, wt, D, m0, n0, acc, lds);

  const int lane = threadIdx.x & 63;
  const int w = threadIdx.x >> 6, wm = w >> 1, wn = w & 1;
  const int lrow = lane & 15, lgrp = lane >> 4;
#pragma unroll
  for (int mi = 0; mi < 4; mi++) {
    int rbase = m0 + wm * 64 + mi * 16 + lgrp * 4;
#pragma unroll
    for (int ni = 0; ni < 4; ni++) {
      int c = n0 + wn * 64 + ni * 16 + lrow;
      int which = c >> 10, cl = c & 1023;
      int hh = cl >> 6, e = cl & 63;
#pragma unroll
      for (int i = 0; i < 4; i++) {
        int r = rbase + i;
        int bb = r >> 11, ss = r & 2047;
        float v = acc[mi][ni][i];
        if (which == 0)      q_ws[((bb * H + hh) * S + ss) * 64 + e] = f2bf(v + bq[cl]);
        else if (which == 1) k_ws[((bb * H + hh) * S + ss) * 64 + e] = f2bf(v + bk[cl]);
        else                 vT_ws[((bb * H + hh) * 64 + e) * S + ss] = f2bf(v + bv[cl]);
      }
    }
  }
}

// Output GEMM: z[8192,1024] = attn_bf @ Wo_t^T + bo   (fp32 out)
__global__ __launch_bounds__(256) void k_out_gemm(const ushort_t* __restrict__ attn_bf,
                                                  const ushort_t* __restrict__ wot,
                                                  const float* __restrict__ bo,
                                                  float* __restrict__ z) {
  __shared__ char lds[16384];
  const int m0 = blockIdx.y * 128, n0 = blockIdx.x * 128;
  f32x4 acc[4][4];
  gemm_core_128(attn_bf, wot, D, m0, n0, acc, lds);

  const int lane = threadIdx.x & 63;
  const int w = threadIdx.x >> 6, wm = w >> 1, wn = w & 1;
  const int lrow = lane & 15, lgrp = lane >> 4;
#pragma unroll
  for (int mi = 0; mi < 4; mi++) {
    int rbase = m0 + wm * 64 + mi * 16 + lgrp * 4;
#pragma unroll
    for (int ni = 0; ni < 4; ni++) {
      int c = n0 + wn * 64 + ni * 16 + lrow;
#pragma unroll
      for (int i = 0; i < 4; i++)
        z[(rbase + i) * D + c] = acc[mi][ni][i] + bo[c];
    }
  }
}

// ---------------- flash attention ----------------
// grid: 1024 blocks = 64 (b,h) x 16 q-tiles of 128 rows. 256 thr = 4 waves x 32 q-rows.
// K-tile/V^T-tile of 64 staged in LDS with XOR-swizzle ((row&7)<<4) on 128B rows.
__global__ __launch_bounds__(256) void k_attn(const ushort_t* __restrict__ q_ws,
                                              const ushort_t* __restrict__ k_ws,
                                              const ushort_t* __restrict__ vT_ws,
                                              ushort_t* __restrict__ attn_bf) {
  __shared__ char lds[8192 + 8192 + 4 * 4096];   // K | V^T | per-wave P
  const int bid = blockIdx.x;
  const int bh = bid >> 4, qt = bid & 15;
  const int bb = bh >> 4, hh = bh & 15;
  const char* qp = (const char*)(q_ws + (size_t)bh * S * 64);
  const char* kp = (const char*)(k_ws + (size_t)bh * S * 64);
  const char* vp = (const char*)(vT_ws + (size_t)bh * 64 * S);

  const int t = threadIdx.x, lane = t & 63, w = t >> 6;
  const int lrow = lane & 15, lgrp = lane >> 4;
  const int q0 = qt * 128 + w * 32;

  char* Klds = lds;
  char* Vlds = lds + 8192;
  char* Plds = lds + 16384 + w * 4096;

  // Q fragments in registers for the whole kernel
  bf16x8 aq[2][2];
#pragma unroll
  for (int m = 0; m < 2; m++)
#pragma unroll
    for (int kk = 0; kk < 2; kk++)
      aq[m][kk] = *(const bf16x8*)(qp + (q0 + m * 16 + lrow) * 128 + kk * 64 + lgrp * 16);

  f32x4 O[2][4];
  float mrun[2][4], lrun[2][4];
#pragma unroll
  for (int m = 0; m < 2; m++) {
#pragma unroll
    for (int eb = 0; eb < 4; eb++) O[m][eb] = f32x4{0.f, 0.f, 0.f, 0.f};
#pragma unroll
    for (int i = 0; i < 4; i++) { mrun[m][i] = -1e30f; lrun[m][i] = 0.f; }
  }

  // staging source offsets for this thread (linear LDS offset -> swizzled src)
  const int o0 = w * 1024 + lane * 16;
  const int r0 = o0 >> 7,        cb0 = (o0 & 127) ^ ((r0 & 7) << 4);
  const int o1 = 4096 + o0;
  const int r1 = o1 >> 7,        cb1 = (o1 & 127) ^ ((r1 & 7) << 4);

  for (int tt = 0; tt < 32; ++tt) {
    const int tbase = tt * 64;
    __syncthreads();
    // K tile: contiguous 8KB at kp + tbase*128
    gload_lds16(kp + tbase * 128 + r0 * 128 + cb0, Klds + w * 1024);
    gload_lds16(kp + tbase * 128 + r1 * 128 + cb1, Klds + 4096 + w * 1024);
    // V^T tile: row e stride 4096B, col byte = tbase*2
    gload_lds16(vp + r0 * 4096 + tbase * 2 + cb0, Vlds + w * 1024);
    gload_lds16(vp + r1 * 4096 + tbase * 2 + cb1, Vlds + 4096 + w * 1024);
    __syncthreads();

    // scores: sc[m][n] = Q(32 rows) x K^T(64 cols) / 8
    f32x4 sc[2][4];
#pragma unroll
    for (int m = 0; m < 2; m++)
#pragma unroll
      for (int n = 0; n < 4; n++) {
        f32x4 a = f32x4{0.f, 0.f, 0.f, 0.f};
#pragma unroll
        for (int kk = 0; kk < 2; kk++) {
          int row = n * 16 + lrow;
          bf16x8 kf = *(const bf16x8*)(Klds + row * 128 + ((kk * 64 + lgrp * 16) ^ ((row & 7) << 4)));
          a = __builtin_amdgcn_mfma_f32_16x16x32_bf16(aq[m][kk], kf, a, 0, 0, 0);
        }
#pragma unroll
        for (int i = 0; i < 4; i++) a[i] *= 0.125f;
        sc[m][n] = a;
      }

    // online softmax (rows = (lgrp)*4 + i, reduce across 16-lane group)
#pragma unroll
    for (int m = 0; m < 2; m++)
#pragma unroll
      for (int i = 0; i < 4; i++) {
        float mx = fmaxf(fmaxf(sc[m][0][i], sc[m][1][i]), fmaxf(sc[m][2][i], sc[m][3][i]));
#pragma unroll
        for (int d = 1; d < 16; d <<= 1) mx = fmaxf(mx, __shfl_xor(mx, d, 64));
        float newm = fmaxf(mrun[m][i], mx);
        float corr = exp2f((mrun[m][i] - newm) * 1.44269504f);
        float rsum = 0.f;
#pragma unroll
        for (int n = 0; n < 4; n++) {
          float p = exp2f((sc[m][n][i] - newm) * 1.44269504f);
          sc[m][n][i] = p;
          rsum += p;
        }
#pragma unroll
        for (int d = 1; d < 16; d <<= 1) rsum += __shfl_xor(rsum, d, 64);
        lrun[m][i] = lrun[m][i] * corr + rsum;
        mrun[m][i] = newm;
#pragma unroll
        for (int eb = 0; eb < 4; eb++) O[m][eb][i] *= corr;
      }

    // P -> per-wave LDS (bf16, swizzled)
#pragma unroll
    for (int m = 0; m < 2; m++)
#pragma unroll
      for (int n = 0; n < 4; n++)
#pragma unroll
        for (int i = 0; i < 4; i++) {
          int rp = m * 16 + lgrp * 4 + i;
          int cb = (n * 16 + lrow) * 2;
          *(ushort_t*)(Plds + rp * 128 + (cb ^ ((rp & 7) << 4))) = f2bf(sc[m][n][i]);
        }

    // PV: O += P[32,64] x V[64,64]
    bf16x8 pa[2][2];
#pragma unroll
    for (int m2 = 0; m2 < 2; m2++)
#pragma unroll
      for (int ks = 0; ks < 2; ks++) {
        int rp = m2 * 16 + lrow;
        pa[m2][ks] = *(const bf16x8*)(Plds + rp * 128 + ((ks * 64 + lgrp * 16) ^ ((rp & 7) << 4)));
      }
#pragma unroll
    for (int eb = 0; eb < 4; eb++)
#pragma unroll
      for (int ks = 0; ks < 2; ks++) {
        int rv = eb * 16 + lrow;
        bf16x8 vf = *(const bf16x8*)(Vlds + rv * 128 + ((ks * 64 + lgrp * 16) ^ ((rv & 7) << 4)));
#pragma unroll
        for (int m2 = 0; m2 < 2; m2++)
          O[m2][eb] = __builtin_amdgcn_mfma_f32_16x16x32_bf16(pa[m2][ks], vf, O[m2][eb], 0, 0, 0);
      }
  }

  // normalize + store attn_bf[b*S + q, h*64 + e]
#pragma unroll
  for (int m = 0; m < 2; m++)
#pragma unroll
    for (int i = 0; i < 4; i++) {
      float inv = 1.f / lrun[m][i];
      int gr = bb * S + qt * 128 + w * 32 + m * 16 + lgrp * 4 + i;
#pragma unroll
      for (int eb = 0; eb < 4; eb++) {
        int c = hh * 64 + eb * 16 + lrow;
        attn_bf[gr * D + c] = f2bf(O[m][eb][i] * inv);
      }
    }
}

// ---------------- residual + layernorm ----------------
__global__ __launch_bounds__(256) void k_ln(const float* __restrict__ z,
                                            const float* __restrict__ x,
                                            const float* __restrict__ lnw,
                                            const float* __restrict__ lnb,
                                            float* __restrict__ out) {
  const int r = blockIdx.x;
  const int t = threadIdx.x, lane = t & 63, w = t >> 6;
  float4 zv = ((const float4*)(z + r * D))[t];
  float4 xv = ((const float4*)(x + r * D))[t];
  float y[4] = {zv.x + xv.x, zv.y + xv.y, zv.z + xv.z, zv.w + xv.w};
  float sum = y[0] + y[1] + y[2] + y[3];
  float sq  = y[0]*y[0] + y[1]*y[1] + y[2]*y[2] + y[3]*y[3];
#pragma unroll
  for (int d = 1; d < 64; d <<= 1) { sum += __shfl_xor(sum, d, 64); sq += __shfl_xor(sq, d, 64); }
  __shared__ float ssum[4], ssq[4];
  if (lane == 0) { ssum[w] = sum; ssq[w] = sq; }
  __syncthreads();
  sum = ssum[0] + ssum[1] + ssum[2] + ssum[3];
  sq  = ssq[0] + ssq[1] + ssq[2] + ssq[3];
  float mean = sum * (1.f / D);
  float var  = sq * (1.f / D) - mean * mean;
  float rstd = rsqrtf(var + 1e-5f);
  float4 wv = ((const float4*)lnw)[t];
  float4 bv = ((const float4*)lnb)[t];
  float4 ov;
  ov.x = (y[0] - mean) * rstd * wv.x + bv.x;
  ov.y = (y[1] - mean) * rstd * wv.y + bv.y;
  ov.z = (y[2] - mean) * rstd * wv.z + bv.z;
  ov.w = (y[3] - mean) * rstd * wv.w + bv.w;
  ((float4*)(out + r * D))[t] = ov;
}

// ---------------- launcher ----------------
extern "C" void kernel_launch(void* const* d_in, const int* in_sizes, int n_in,
                              void* d_out, int out_size, void* d_ws, size_t ws_size,
                              hipStream_t stream) {
  const float* x   = (const float*)d_in[0];
  const float* Wq  = (const float*)d_in[1];
  const float* bq  = (const float*)d_in[2];
  const float* Wk  = (const float*)d_in[3];
  const float* bk  = (const float*)d_in[4];
  const float* Wv  = (const float*)d_in[5];
  const float* bv  = (const float*)d_in[6];
  const float* Wo  = (const float*)d_in[7];
  const float* bo  = (const float*)d_in[8];
  const float* lnw = (const float*)d_in[9];
  const float* lnb = (const float*)d_in[10];

  char* ws = (char*)d_ws;
  // layout (z aliases xb+q_ws, both dead before out_gemm writes z)
  ushort_t* xb    = (ushort_t*)(ws + 0);           // 16,777,216
  ushort_t* q_ws  = (ushort_t*)(ws + 16777216);    // 16,777,216
  ushort_t* wt    = (ushort_t*)(ws + 33554432);    //  6,291,456
  ushort_t* wot   = (ushort_t*)(ws + 39845888);    //  2,097,152
  ushort_t* k_ws  = (ushort_t*)(ws + 41943040);    // 16,777,216
  ushort_t* vT_ws = (ushort_t*)(ws + 58720256);    // 16,777,216
  ushort_t* attn  = (ushort_t*)(ws + 75497472);    // 16,777,216  (total 92,274,688)
  float*    z     = (float*)(ws + 0);              // 33,554,432 alias over xb+q_ws

  k_conv_x<<<8192, 256, 0, stream>>>(x, xb);
  k_conv_w<<<12288, 256, 0, stream>>>(Wq, Wk, Wv, wt);
  k_conv_wo<<<4096, 256, 0, stream>>>(Wo, wot);
  k_qkv_gemm<<<dim3(NQKV / 128, BS / 128), 256, 0, stream>>>(xb, wt, bq, bk, bv, q_ws, k_ws, vT_ws);
  k_attn<<<B * H * (S / 128), 256, 0, stream>>>(q_ws, k_ws, vT_ws, attn);
  k_out_gemm<<<dim3(D / 128, BS / 128), 256, 0, stream>>>(attn, wot, bo, z);
  k_ln<<<BS, 256, 0, stream>>>(z, x, lnw, lnb, (float*)d_out);
}

// Round 6
// 366.382 us; speedup vs baseline: 1.3738x; 1.3738x over previous
//
#include <hip/hip_runtime.h>
#include <hip/hip_bf16.h>
#include <stdint.h>

// ---- problem constants ----
constexpr int D  = 1024;
constexpr int H  = 16;
constexpr int DH = 64;
constexpr int B  = 4;
constexpr int S  = 2048;
constexpr int BS = B * S;          // 8192
constexpr int NQKV = 3 * D;        // 3072

typedef __attribute__((ext_vector_type(8))) short bf16x8;
typedef __attribute__((ext_vector_type(4))) float f32x4;
typedef __attribute__((ext_vector_type(16))) float f32x16;
typedef __attribute__((ext_vector_type(4))) unsigned short us4;
typedef __attribute__((ext_vector_type(4))) unsigned int u32x4;
typedef unsigned short ushort_t;

using gu32 = __attribute__((address_space(1))) unsigned int;
using lu32 = __attribute__((address_space(3))) unsigned int;

__device__ __forceinline__ void gload_lds16(const void* g, void* l) {
  __builtin_amdgcn_global_load_lds((gu32*)g, (lu32*)l, 16, 0, 0);
}

__device__ __forceinline__ ushort_t f2bf(float f) {
  uint32_t u = __builtin_bit_cast(uint32_t, f);
  u += 0x7FFFu + ((u >> 16) & 1u);
  return (ushort_t)(u >> 16);
}

// packed f32x2 -> bf16x2 (src0 -> low 16, src1 -> high 16)
__device__ __forceinline__ unsigned cvtpk(float lo, float hi) {
  unsigned r;
  asm("v_cvt_pk_bf16_f32 %0, %1, %2" : "=v"(r) : "v"(lo), "v"(hi));
  return r;
}

// Cross-half exchange (semantics-unambiguous, replaces permlane32_swap):
// lo-lane (hi=0): keeps w0,w1; receives other-half-lane's w0,w1 into w2,w3.
// hi-lane (hi=1): keeps w2,w3; receives other-half-lane's w2,w3 into w0,w1.
__device__ __forceinline__ void xch4(unsigned& w0, unsigned& w1,
                                     unsigned& w2, unsigned& w3, int hi) {
  unsigned sx = hi ? w0 : w2;               // what this lane sends
  unsigned sy = hi ? w1 : w3;
  sx = (unsigned)__shfl_xor((int)sx, 32, 64);
  sy = (unsigned)__shfl_xor((int)sy, 32, 64);
  if (hi) { w0 = sx; w1 = sy; } else { w2 = sx; w3 = sy; }
}

// ---------------- conversion kernels ----------------
__global__ __launch_bounds__(256) void k_conv_x(const float* __restrict__ x,
                                                ushort_t* __restrict__ xb) {
  int i = (blockIdx.x * 256 + threadIdx.x) * 4;
  float4 v = *(const float4*)(x + i);
  us4 o;
  o[0] = f2bf(v.x); o[1] = f2bf(v.y); o[2] = f2bf(v.z); o[3] = f2bf(v.w);
  *(us4*)(xb + i) = o;
}

// Wcat_t [3072][1024] bf16: row c -> (Wq|Wk|Wv)[h, d, e] with h=cl>>6, e=cl&63
__global__ __launch_bounds__(256) void k_conv_w(const float* __restrict__ Wq,
                                                const float* __restrict__ Wk,
                                                const float* __restrict__ Wv,
                                                ushort_t* __restrict__ wt) {
  int idx = blockIdx.x * 256 + threadIdx.x;   // 3072*1024
  int c = idx >> 10, d = idx & 1023;
  int cl = c & 1023;
  int hh = cl >> 6, e = cl & 63;
  const float* src = (c < 1024) ? Wq : ((c < 2048) ? Wk : Wv);
  wt[idx] = f2bf(src[(hh * D + d) * DH + e]);
}

// Wo_t [1024][1024] bf16: wot[c][d] = Wo[d][c]
__global__ __launch_bounds__(256) void k_conv_wo(const float* __restrict__ Wo,
                                                 ushort_t* __restrict__ wot) {
  int idx = blockIdx.x * 256 + threadIdx.x;   // 1024*1024
  int c = idx >> 10, d = idx & 1023;
  wot[idx] = f2bf(Wo[d * D + c]);
}

// ---------------- GEMM core: C[128,128] tile = A[M,K] @ Bt[N,K]^T (bf16) ----------------
__device__ __forceinline__ void gemm_core_128(const ushort_t* __restrict__ A,
                                              const ushort_t* __restrict__ Bt,
                                              int K, int m0, int n0,
                                              f32x4 acc[4][4], char* lds) {
  const int t    = threadIdx.x;
  const int lane = t & 63;
  const int w    = t >> 6;
  const int wm   = w >> 1, wn = w & 1;
  const int lrow = lane & 15, lgk = (lane >> 4) * 16;

#pragma unroll
  for (int i = 0; i < 4; i++)
#pragma unroll
    for (int j = 0; j < 4; j++) acc[i][j] = f32x4{0.f, 0.f, 0.f, 0.f};

  char* ldsA = lds;
  char* ldsB = lds + 8192;
  const long strideK = (long)K * 2;
  const char* gA = (const char*)A + (long)(m0 + (t >> 2)) * strideK + (t & 3) * 16;
  const char* gB = (const char*)Bt + (long)(n0 + (t >> 2)) * strideK + (t & 3) * 16;

  for (int kt = 0; kt < K; kt += 32) {
    const char* sA = gA + kt * 2;
    const char* sB = gB + kt * 2;
    gload_lds16(sA,                ldsA + w * 1024);
    gload_lds16(sA + 64 * strideK, ldsA + 4096 + w * 1024);
    gload_lds16(sB,                ldsB + w * 1024);
    gload_lds16(sB + 64 * strideK, ldsB + 4096 + w * 1024);
    __syncthreads();

    bf16x8 af[4], bfr[4];
#pragma unroll
    for (int mi = 0; mi < 4; mi++)
      af[mi] = *(const bf16x8*)(ldsA + (wm * 64 + mi * 16 + lrow) * 64 + lgk);
#pragma unroll
    for (int ni = 0; ni < 4; ni++)
      bfr[ni] = *(const bf16x8*)(ldsB + (wn * 64 + ni * 16 + lrow) * 64 + lgk);
#pragma unroll
    for (int mi = 0; mi < 4; mi++)
#pragma unroll
      for (int ni = 0; ni < 4; ni++)
        acc[mi][ni] = __builtin_amdgcn_mfma_f32_16x16x32_bf16(af[mi], bfr[ni], acc[mi][ni], 0, 0, 0);
    __syncthreads();
  }
}

// QKV GEMM epilogue: bias; Q scaled by 0.125*log2e (attn works in exp2 domain)
__global__ __launch_bounds__(256) void k_qkv_gemm(const ushort_t* __restrict__ xb,
                                                  const ushort_t* __restrict__ wt,
                                                  const float* __restrict__ bq,
                                                  const float* __restrict__ bk,
                                                  const float* __restrict__ bv,
                                                  ushort_t* __restrict__ q_ws,
                                                  ushort_t* __restrict__ k_ws,
                                                  ushort_t* __restrict__ vT_ws) {
  __shared__ char lds[16384];
  const int m0 = blockIdx.y * 128, n0 = blockIdx.x * 128;
  f32x4 acc[4][4];
  gemm_core_128(xb, wt, D, m0, n0, acc, lds);

  constexpr float QSC = 0.18033688011112042f;  // 0.125 * log2(e)
  const int lane = threadIdx.x & 63;
  const int w = threadIdx.x >> 6, wm = w >> 1, wn = w & 1;
  const int lrow = lane & 15, lgrp = lane >> 4;
#pragma unroll
  for (int mi = 0; mi < 4; mi++) {
    int rbase = m0 + wm * 64 + mi * 16 + lgrp * 4;
#pragma unroll
    for (int ni = 0; ni < 4; ni++) {
      int c = n0 + wn * 64 + ni * 16 + lrow;
      int which = c >> 10, cl = c & 1023;
      int hh = cl >> 6, e = cl & 63;
#pragma unroll
      for (int i = 0; i < 4; i++) {
        int r = rbase + i;
        int bb = r >> 11, ss = r & 2047;
        float v = acc[mi][ni][i];
        if (which == 0)      q_ws[((bb * H + hh) * S + ss) * 64 + e] = f2bf((v + bq[cl]) * QSC);
        else if (which == 1) k_ws[((bb * H + hh) * S + ss) * 64 + e] = f2bf(v + bk[cl]);
        else                 vT_ws[((bb * H + hh) * 64 + e) * S + ss] = f2bf(v + bv[cl]);
      }
    }
  }
}

// Output GEMM: z[8192,1024] = attn_bf @ Wo_t^T + bo   (fp32 out)
__global__ __launch_bounds__(256) void k_out_gemm(const ushort_t* __restrict__ attn_bf,
                                                  const ushort_t* __restrict__ wot,
                                                  const float* __restrict__ bo,
                                                  float* __restrict__ z) {
  __shared__ char lds[16384];
  const int m0 = blockIdx.y * 128, n0 = blockIdx.x * 128;
  f32x4 acc[4][4];
  gemm_core_128(attn_bf, wot, D, m0, n0, acc, lds);

  const int lane = threadIdx.x & 63;
  const int w = threadIdx.x >> 6, wm = w >> 1, wn = w & 1;
  const int lrow = lane & 15, lgrp = lane >> 4;
#pragma unroll
  for (int mi = 0; mi < 4; mi++) {
    int rbase = m0 + wm * 64 + mi * 16 + lgrp * 4;
#pragma unroll
    for (int ni = 0; ni < 4; ni++) {
      int c = n0 + wn * 64 + ni * 16 + lrow;
#pragma unroll
      for (int i = 0; i < 4; i++)
        z[(rbase + i) * D + c] = acc[mi][ni][i] + bo[c];
    }
  }
}

// ---------------- flash attention: swapped-QK^T 32x32 structure ----------------
// grid 1024 = 64 bh x 16 q-tiles of 128 rows; 256 thr = 4 waves x 32 q-rows.
// Swapped MFMA: S^T = mfma(K,Q) -> each lane owns one q-row (q=lane&31); softmax
// lane-local; P packed via v_cvt_pk_bf16_f32 + shfl_xor(32) cross-half exchange;
// O^T = mfma(Vt,P).
__global__ __launch_bounds__(256) void k_attn(const ushort_t* __restrict__ q_ws,
                                              const ushort_t* __restrict__ k_ws,
                                              const ushort_t* __restrict__ vT_ws,
                                              ushort_t* __restrict__ attn_bf) {
  __shared__ __align__(16) char lds[2][16384];   // [buf][K 8KB | Vt 8KB]
  const int bid = blockIdx.x;
  // XCD swizzle: all 16 q-tiles of one bh land on the same XCD (bid%8 fixed)
  const int bh = ((bid & 7) << 3) | (bid >> 7);
  const int qt = (bid >> 3) & 15;
  const int bb = bh >> 4, hh = bh & 15;
  const char* qp = (const char*)(q_ws + (size_t)bh * S * 64);
  const char* kp = (const char*)(k_ws + (size_t)bh * S * 64);
  const char* vp = (const char*)(vT_ws + (size_t)bh * 64 * S);

  const int t = threadIdx.x, lane = t & 63, w = t >> 6;
  const int l31 = lane & 31, hi = lane >> 5;
  const int swz = (lane & 7) << 4;

  // staging: linear LDS dest, inverse-swizzled global source (16B chunks)
  const int o0 = t * 16;
  const int r0 = o0 >> 7, c0 = (o0 & 127) ^ ((r0 & 7) << 4);
  const int o1 = 4096 + t * 16;
  const int r1 = o1 >> 7, c1 = (o1 & 127) ^ ((r1 & 7) << 4);

  // Q fragments: Q[q=l31][d = w16*16 + hi*8 + j], pre-scaled by 0.125*log2e
  const char* qrow = qp + (size_t)(qt * 128 + w * 32 + l31) * 128;
  bf16x8 qf[4];
#pragma unroll
  for (int w16 = 0; w16 < 4; ++w16)
    qf[w16] = *(const bf16x8*)(qrow + w16 * 32 + hi * 16);

  f32x16 oA, oB;     // O^T accs: d 0-31 / 32-63 (d = (r&3)+8*(r>>2)+4*hi +32*do2)
#pragma unroll
  for (int r = 0; r < 16; ++r) { oA[r] = 0.f; oB[r] = 0.f; }
  float m_run = -1e30f, l_run = 0.f;

  // prologue: stage tile 0 into buf 0
  gload_lds16(kp + r0 * 128 + c0,  lds[0] + w * 1024);
  gload_lds16(kp + r1 * 128 + c1,  lds[0] + 4096 + w * 1024);
  gload_lds16(vp + r0 * 4096 + c0, lds[0] + 8192 + w * 1024);
  gload_lds16(vp + r1 * 4096 + c1, lds[0] + 12288 + w * 1024);
  __syncthreads();

  for (int tt = 0; tt < 32; ++tt) {
    const int cur = tt & 1;
    const char* Klds = lds[cur];
    const char* Vlds = lds[cur] + 8192;
    if (tt + 1 < 32) {                       // prefetch next tile (2-phase pipeline)
      char* dN = lds[cur ^ 1];
      const int nb = tt + 1;
      gload_lds16(kp + nb * 8192 + r0 * 128 + c0, dN + w * 1024);
      gload_lds16(kp + nb * 8192 + r1 * 128 + c1, dN + 4096 + w * 1024);
      gload_lds16(vp + r0 * 4096 + nb * 128 + c0, dN + 8192 + w * 1024);
      gload_lds16(vp + r1 * 4096 + nb * 128 + c1, dN + 12288 + w * 1024);
    }

    // QK^T: S^T[kv][q], kv-tiles t2=0 (rows 0-31) and t2=1 (rows 32-63)
    f32x16 sA, sB;
#pragma unroll
    for (int r = 0; r < 16; ++r) { sA[r] = 0.f; sB[r] = 0.f; }
    const char* kb = Klds + l31 * 128;
    __builtin_amdgcn_s_setprio(1);
#pragma unroll
    for (int w16 = 0; w16 < 4; ++w16) {
      const int col = w16 * 32 + hi * 16;
      bf16x8 k0 = *(const bf16x8*)(kb + (col ^ swz));
      bf16x8 k1 = *(const bf16x8*)(kb + 4096 + (col ^ swz));
      sA = __builtin_amdgcn_mfma_f32_32x32x16_bf16(k0, qf[w16], sA, 0, 0, 0);
      sB = __builtin_amdgcn_mfma_f32_32x32x16_bf16(k1, qf[w16], sB, 0, 0, 0);
    }
    __builtin_amdgcn_s_setprio(0);

    // lane-local online softmax (exp2 domain; scores pre-scaled by log2e/8)
    float mx = sA[0];
#pragma unroll
    for (int r = 1; r < 16; ++r) mx = fmaxf(mx, sA[r]);
#pragma unroll
    for (int r = 0; r < 16; ++r) mx = fmaxf(mx, sB[r]);
    mx = fmaxf(mx, __shfl_xor(mx, 32, 64));
    if (__any(mx > m_run + 11.5416f)) {      // defer-max (T13, THR = 8*log2e)
      float nm = fmaxf(m_run, mx);
      float corr = __builtin_amdgcn_exp2f(m_run - nm);
      l_run *= corr;
#pragma unroll
      for (int r = 0; r < 16; ++r) { oA[r] *= corr; oB[r] *= corr; }
      m_run = nm;
    }
    float rs = 0.f;
#pragma unroll
    for (int r = 0; r < 16; ++r) {
      sA[r] = __builtin_amdgcn_exp2f(sA[r] - m_run);
      sB[r] = __builtin_amdgcn_exp2f(sB[r] - m_run);
      rs += sA[r] + sB[r];
    }
    rs += __shfl_xor(rs, 32, 64);
    l_run += rs;

    // P -> bf16 pack + cross-half exchange => PV B-operand fragments
    unsigned pk0[8], pk1[8];
#pragma unroll
    for (int g = 0; g < 4; ++g) {
      pk0[2*g]   = cvtpk(sA[4*g],   sA[4*g+1]);
      pk0[2*g+1] = cvtpk(sA[4*g+2], sA[4*g+3]);
      pk1[2*g]   = cvtpk(sB[4*g],   sB[4*g+1]);
      pk1[2*g+1] = cvtpk(sB[4*g+2], sB[4*g+3]);
    }
    xch4(pk0[0], pk0[1], pk0[2], pk0[3], hi);
    xch4(pk0[4], pk0[5], pk0[6], pk0[7], hi);
    xch4(pk1[0], pk1[1], pk1[2], pk1[3], hi);
    xch4(pk1[4], pk1[5], pk1[6], pk1[7], hi);
    bf16x8 pf[4];
    pf[0] = __builtin_bit_cast(bf16x8, u32x4{pk0[0], pk0[1], pk0[2], pk0[3]});
    pf[1] = __builtin_bit_cast(bf16x8, u32x4{pk0[4], pk0[5], pk0[6], pk0[7]});
    pf[2] = __builtin_bit_cast(bf16x8, u32x4{pk1[0], pk1[1], pk1[2], pk1[3]});
    pf[3] = __builtin_bit_cast(bf16x8, u32x4{pk1[4], pk1[5], pk1[6], pk1[7]});

    // PV: O^T[d][q] += Vt[d][kv] . P[q][kv]
    const char* vb = Vlds + l31 * 128;
    __builtin_amdgcn_s_setprio(1);
#pragma unroll
    for (int ks = 0; ks < 4; ++ks) {
      const int colv = ks * 32 + hi * 16;
      bf16x8 v0 = *(const bf16x8*)(vb + (colv ^ swz));
      bf16x8 v1 = *(const bf16x8*)(vb + 4096 + (colv ^ swz));
      oA = __builtin_amdgcn_mfma_f32_32x32x16_bf16(v0, pf[ks], oA, 0, 0, 0);
      oB = __builtin_amdgcn_mfma_f32_32x32x16_bf16(v1, pf[ks], oB, 0, 0, 0);
    }
    __builtin_amdgcn_s_setprio(0);

    __syncthreads();   // next buf staged (vmcnt drained) + this buf free to overwrite
  }

  // epilogue: normalize, pack to bf16, exchange to d-contiguous runs, 16B stores
  const float inv = 1.f / l_run;
  unsigned ok0[8], ok1[8];
#pragma unroll
  for (int g = 0; g < 4; ++g) {
    ok0[2*g]   = cvtpk(oA[4*g] * inv,   oA[4*g+1] * inv);
    ok0[2*g+1] = cvtpk(oA[4*g+2] * inv, oA[4*g+3] * inv);
    ok1[2*g]   = cvtpk(oB[4*g] * inv,   oB[4*g+1] * inv);
    ok1[2*g+1] = cvtpk(oB[4*g+2] * inv, oB[4*g+3] * inv);
  }
  xch4(ok0[0], ok0[1], ok0[2], ok0[3], hi);
  xch4(ok0[4], ok0[5], ok0[6], ok0[7], hi);
  xch4(ok1[0], ok1[1], ok1[2], ok1[3], hi);
  xch4(ok1[4], ok1[5], ok1[6], ok1[7], hi);

  const int grow = bb * S + qt * 128 + w * 32 + l31;
  ushort_t* orow = attn_bf + (size_t)grow * 1024 + hh * 64;
  *(u32x4*)(orow + 8 * hi)      = u32x4{ok0[0], ok0[1], ok0[2], ok0[3]};
  *(u32x4*)(orow + 16 + 8 * hi) = u32x4{ok0[4], ok0[5], ok0[6], ok0[7]};
  *(u32x4*)(orow + 32 + 8 * hi) = u32x4{ok1[0], ok1[1], ok1[2], ok1[3]};
  *(u32x4*)(orow + 48 + 8 * hi) = u32x4{ok1[4], ok1[5], ok1[6], ok1[7]};
}

// ---------------- residual + layernorm ----------------
__global__ __launch_bounds__(256) void k_ln(const float* __restrict__ z,
                                            const float* __restrict__ x,
                                            const float* __restrict__ lnw,
                                            const float* __restrict__ lnb,
                                            float* __restrict__ out) {
  const int r = blockIdx.x;
  const int t = threadIdx.x, lane = t & 63, w = t >> 6;
  float4 zv = ((const float4*)(z + r * D))[t];
  float4 xv = ((const float4*)(x + r * D))[t];
  float y[4] = {zv.x + xv.x, zv.y + xv.y, zv.z + xv.z, zv.w + xv.w};
  float sum = y[0] + y[1] + y[2] + y[3];
  float sq  = y[0]*y[0] + y[1]*y[1] + y[2]*y[2] + y[3]*y[3];
#pragma unroll
  for (int d = 1; d < 64; d <<= 1) { sum += __shfl_xor(sum, d, 64); sq += __shfl_xor(sq, d, 64); }
  __shared__ float ssum[4], ssq[4];
  if (lane == 0) { ssum[w] = sum; ssq[w] = sq; }
  __syncthreads();
  sum = ssum[0] + ssum[1] + ssum[2] + ssum[3];
  sq  = ssq[0] + ssq[1] + ssq[2] + ssq[3];
  float mean = sum * (1.f / D);
  float var  = sq * (1.f / D) - mean * mean;
  float rstd = rsqrtf(var + 1e-5f);
  float4 wv = ((const float4*)lnw)[t];
  float4 bv = ((const float4*)lnb)[t];
  float4 ov;
  ov.x = (y[0] - mean) * rstd * wv.x + bv.x;
  ov.y = (y[1] - mean) * rstd * wv.y + bv.y;
  ov.z = (y[2] - mean) * rstd * wv.z + bv.z;
  ov.w = (y[3] - mean) * rstd * wv.w + bv.w;
  ((float4*)(out + r * D))[t] = ov;
}

// ---------------- launcher ----------------
extern "C" void kernel_launch(void* const* d_in, const int* in_sizes, int n_in,
                              void* d_out, int out_size, void* d_ws, size_t ws_size,
                              hipStream_t stream) {
  const float* x   = (const float*)d_in[0];
  const float* Wq  = (const float*)d_in[1];
  const float* bq  = (const float*)d_in[2];
  const float* Wk  = (const float*)d_in[3];
  const float* bk  = (const float*)d_in[4];
  const float* Wv  = (const float*)d_in[5];
  const float* bv  = (const float*)d_in[6];
  const float* Wo  = (const float*)d_in[7];
  const float* bo  = (const float*)d_in[8];
  const float* lnw = (const float*)d_in[9];
  const float* lnb = (const float*)d_in[10];

  char* ws = (char*)d_ws;
  ushort_t* xb    = (ushort_t*)(ws + 0);           // 16,777,216
  ushort_t* q_ws  = (ushort_t*)(ws + 16777216);    // 16,777,216
  ushort_t* wt    = (ushort_t*)(ws + 33554432);    //  6,291,456
  ushort_t* wot   = (ushort_t*)(ws + 39845888);    //  2,097,152
  ushort_t* k_ws  = (ushort_t*)(ws + 41943040);    // 16,777,216
  ushort_t* vT_ws = (ushort_t*)(ws + 58720256);    // 16,777,216
  ushort_t* attn  = (ushort_t*)(ws + 75497472);    // 16,777,216  (total 92,274,688)
  float*    z     = (float*)(ws + 0);              // 33,554,432 alias over xb+q_ws

  k_conv_x<<<8192, 256, 0, stream>>>(x, xb);
  k_conv_w<<<12288, 256, 0, stream>>>(Wq, Wk, Wv, wt);
  k_conv_wo<<<4096, 256, 0, stream>>>(Wo, wot);
  k_qkv_gemm<<<dim3(NQKV / 128, BS / 128), 256, 0, stream>>>(xb, wt, bq, bk, bv, q_ws, k_ws, vT_ws);
  k_attn<<<B * H * (S / 128), 256, 0, stream>>>(q_ws, k_ws, vT_ws, attn);
  k_out_gemm<<<dim3(D / 128, BS / 128), 256, 0, stream>>>(attn, wot, bo, z);
  k_ln<<<BS, 256, 0, stream>>>(z, x, lnw, lnb, (float*)d_out);
}